// Round 6
// baseline (136.152 us; speedup 1.0000x reference)
//
#include <hip/hip_runtime.h>

#define NTOK 32768
#define CDIM 256
#define KCODE 1024
#define C4 64   // CDIM/4

typedef __bf16 bf16x8 __attribute__((ext_vector_type(8)));
typedef float  f32x4  __attribute__((ext_vector_type(4)));
typedef const __attribute__((address_space(1))) void* as1cvp;
typedef __attribute__((address_space(3))) void* as3vp;

__device__ __forceinline__ unsigned long long umin64(unsigned long long a, unsigned long long b) { return a < b ? a : b; }
__device__ __forceinline__ unsigned long long umax64(unsigned long long a, unsigned long long b) { return a > b ? a : b; }

// ---------------- K1: normalize codebook -> en fp32, en2, eh/el bf16 --------
__global__ void k_norm_emb(const float* __restrict__ emb,
                           float* __restrict__ en, float* __restrict__ en2,
                           __bf16* __restrict__ eh, __bf16* __restrict__ el) {
    int k = blockIdx.x;
    int l = threadIdx.x;               // 64 lanes, 4 floats each
    float4 v = reinterpret_cast<const float4*>(emb)[k * C4 + l];
    float ss = v.x*v.x + v.y*v.y + v.z*v.z + v.w*v.w;
    #pragma unroll
    for (int o = 32; o >= 1; o >>= 1) ss += __shfl_xor(ss, o, 64);
    float den = fmaxf(sqrtf(ss), 1e-12f);
    float4 e;
    e.x = v.x / den; e.y = v.y / den; e.z = v.z / den; e.w = v.w / den;
    reinterpret_cast<float4*>(en)[k * C4 + l] = e;
    float s2 = e.x*e.x + e.y*e.y + e.z*e.z + e.w*e.w;
    #pragma unroll
    for (int o = 32; o >= 1; o >>= 1) s2 += __shfl_xor(s2, o, 64);
    if (l == 0) en2[k] = s2;

    __bf16* ehp = eh + (size_t)k * CDIM + 4 * l;
    __bf16* elp = el + (size_t)k * CDIM + 4 * l;
    float ev[4] = {e.x, e.y, e.z, e.w};
    #pragma unroll
    for (int q = 0; q < 4; ++q) {
        __bf16 h = (__bf16)ev[q];
        ehp[q] = h;
        elp[q] = (__bf16)(ev[q] - (float)h);
    }
}

// ---------------- K2: transpose+normalize z -> znt fp32, znt2, zh/zl bf16 ---
__global__ void k_norm_z(const float* __restrict__ z,
                         float* __restrict__ znt, float* __restrict__ znt2,
                         __bf16* __restrict__ zh, __bf16* __restrict__ zl) {
    __shared__ float zsb[CDIM * 32];   // 32 KB, [c][ (tok+c)&31 ]
    __shared__ float ssp[256];
    __shared__ float dens[32];
    int tid = threadIdx.x;
    int t0  = blockIdx.x * 32;
    int n   = t0 >> 10;
    int thw0 = t0 & 1023;

    int l = tid & 31, grp = tid >> 5;          // 8 c-stripes
    const float* zb = z + (((size_t)(n * CDIM)) << 10) + thw0 + l;
    float ss = 0.f;
    int c0 = grp * 32;
    for (int cc = 0; cc < 32; ++cc) {
        int c = c0 + cc;
        float v = zb[((size_t)c) << 10];
        zsb[c * 32 + ((l + c) & 31)] = v;
        ss += v * v;
    }
    ssp[tid] = ss;
    __syncthreads();
    if (tid < 32) {
        float tot = 0.f;
        #pragma unroll
        for (int g = 0; g < 8; ++g) tot += ssp[g * 32 + tid];
        dens[tid] = fmaxf(sqrtf(tot), 1e-12f);
    }
    __syncthreads();

    int l2 = tid & 63, tg = tid >> 6;          // 4 token-groups of 8
    for (int it = 0; it < 8; ++it) {
        int tok = tg * 8 + it;
        float den = dens[tok];
        float s2 = 0.f;
        #pragma unroll
        for (int cq = 0; cq < 4; ++cq) {
            int c = cq * 64 + l2;
            float v = zsb[c * 32 + ((tok + c) & 31)] / den;
            size_t off = ((size_t)(t0 + tok)) * CDIM + c;
            znt[off] = v;
            __bf16 h = (__bf16)v;
            zh[off] = h;
            zl[off] = (__bf16)(v - (float)h);
            s2 += v * v;
        }
        #pragma unroll
        for (int o = 32; o >= 1; o >>= 1) s2 += __shfl_xor(s2, o, 64);
        if (l2 == 0) znt2[t0 + tok] = s2;
    }
}

// ---------------- K3: split-bf16 MFMA GEMM + top-2 + fused fp32 fixup -------
// 512 blocks x 256 threads (4 waves). BM=64 tokens (16/wave), 64 chunks of 16
// codes. LDS 37KB -> 4 blocks/CU (16 waves) for LDS-pipe utilization. A
// (zh/zl) hoisted (64 VGPR); B double-buffered via global_load_lds with
// pre-swizzled source. 3-way accumulator split = 3 independent MFMA chains.
__global__ __launch_bounds__(256, 4) void k_mfma(
        const __bf16* __restrict__ zh, const __bf16* __restrict__ zl,
        const __bf16* __restrict__ eh, const __bf16* __restrict__ el,
        const float* __restrict__ en2g,
        const float* __restrict__ znt, const float* __restrict__ znt2,
        const float* __restrict__ en,
        int* __restrict__ idxb, float* __restrict__ idxf) {
    __shared__ __bf16 ebuf[2][2][16 * 256];    // [buf][h/l], 8KB each = 32KB
    __shared__ float en2s[KCODE];              // 4KB
    __shared__ unsigned long long cand[64][2]; // 1KB

    int tid = threadIdx.x;
    int l = tid & 63, wid = tid >> 6;
    int t0 = blockIdx.x * 64;
    int row = l & 15, kg = l >> 4;             // frag row (code col) / k-group

    for (int i = tid; i < KCODE; i += 256) en2s[i] = en2g[i];

    // hoist A: wave wid owns tokens t0+wid*16+row; 8 ksteps x {hi,lo} = 64 VGPR
    bf16x8 ah[8], al_[8];
    {
        size_t tok = (size_t)(t0 + wid * 16 + row);
        const __bf16* ph = zh + tok * CDIM + kg * 8;
        const __bf16* pl = zl + tok * CDIM + kg * 8;
        #pragma unroll
        for (int ks = 0; ks < 8; ++ks) {
            ah[ks]  = *reinterpret_cast<const bf16x8*>(ph + ks * 32);
            al_[ks] = *reinterpret_cast<const bf16x8*>(pl + ks * 32);
        }
    }

    // top-2 keys per lane: 4 token-rows
    unsigned long long b1[4], b2[4];
    #pragma unroll
    for (int i = 0; i < 4; ++i) { b1[i] = ~0ull; b2[i] = ~0ull; }

    // stage one 16-code chunk (hi+lo) into ebuf[buf] with XOR swizzle.
    // stored slot = c16 ^ (code & 15); dest is lane-linear (wave-uniform base).
    auto stage = [&](int buf, int ch) {
        #pragma unroll
        for (int a = 0; a < 2; ++a) {
            const __bf16* src = a ? el : eh;
            #pragma unroll
            for (int i2 = 0; i2 < 2; ++i2) {
                int s = i2 * 256 + tid;
                int code = s >> 5, c16 = s & 31;
                int gslot = c16 ^ (code & 15);
                const __bf16* gp = src + ((size_t)(ch * 16 + code)) * CDIM + gslot * 8;
                __bf16* ld = &ebuf[buf][a][0] + ((size_t)(i2 * 256 + wid * 64)) * 8;
                __builtin_amdgcn_global_load_lds((as1cvp)gp, (as3vp)ld, 16, 0, 0);
            }
        }
    };

    stage(0, 0);
    __syncthreads();
    #pragma unroll 2
    for (int ch = 0; ch < 64; ++ch) {
        int cur = ch & 1;
        if (ch < 63) stage(cur ^ 1, ch + 1);

        f32x4 a0, a1, a2;
        #pragma unroll
        for (int r = 0; r < 4; ++r) { a0[r] = 0.f; a1[r] = 0.f; a2[r] = 0.f; }

        #pragma unroll
        for (int ks = 0; ks < 8; ++ks) {
            int slot = (ks * 4 + kg) ^ row;
            bf16x8 bh = *reinterpret_cast<const bf16x8*>(&ebuf[cur][0][row * 256 + slot * 8]);
            bf16x8 bl = *reinterpret_cast<const bf16x8*>(&ebuf[cur][1][row * 256 + slot * 8]);
            a0 = __builtin_amdgcn_mfma_f32_16x16x32_bf16(ah[ks],  bh, a0, 0, 0, 0);
            a1 = __builtin_amdgcn_mfma_f32_16x16x32_bf16(ah[ks],  bl, a1, 0, 0, 0);
            a2 = __builtin_amdgcn_mfma_f32_16x16x32_bf16(al_[ks], bh, a2, 0, 0, 0);
        }

        // selection epilogue: d' = e2 - 2*dot; code col = lane&15
        int code = ch * 16 + row;
        float e2v = en2s[code];
        #pragma unroll
        for (int r = 0; r < 4; ++r) {
            float d = fmaf(-2.0f, (a0[r] + a1[r]) + a2[r], e2v);
            unsigned ub = __float_as_uint(d);
            ub = (ub & 0x80000000u) ? ~ub : (ub | 0x80000000u);
            unsigned long long key = ((unsigned long long)ub << 32) | (unsigned)code;
            if (key < b1[r]) { b2[r] = b1[r]; b1[r] = key; }
            else if (key < b2[r]) { b2[r] = key; }
        }
        __syncthreads();
    }

    // butterfly top-2 merge across the 16 code-col lanes
    #pragma unroll
    for (int i = 0; i < 4; ++i) {
        #pragma unroll
        for (int off = 1; off < 16; off <<= 1) {
            unsigned long long o1 = __shfl_xor(b1[i], off, 16);
            unsigned long long o2 = __shfl_xor(b2[i], off, 16);
            unsigned long long m1 = umin64(b1[i], o1);
            unsigned long long m2 = umin64(umax64(b1[i], o1), umin64(b2[i], o2));
            b1[i] = m1; b2[i] = m2;
        }
    }
    if ((l & 15) == 0) {
        #pragma unroll
        for (int r = 0; r < 4; ++r) {
            int tl = wid * 16 + kg * 4 + r;    // C/D row = token row
            cand[tl][0] = b1[r];
            cand[tl][1] = b2[r];
        }
    }
    __syncthreads();

    // fused fp32 fixup: 4 threads per token, 64 dims each
    {
        int tl = tid >> 2, q = tid & 3;
        int t = t0 + tl;
        unsigned c1 = (unsigned)cand[tl][0];
        unsigned c2 = (unsigned)cand[tl][1];
        const float4* zp  = reinterpret_cast<const float4*>(znt) + (size_t)t  * C4 + q * 16;
        const float4* eap = reinterpret_cast<const float4*>(en)  + (size_t)c1 * C4 + q * 16;
        const float4* ebp = reinterpret_cast<const float4*>(en)  + (size_t)c2 * C4 + q * 16;
        float da = 0.f, db = 0.f;
        #pragma unroll
        for (int i = 0; i < 16; ++i) {
            float4 zv = zp[i], av = eap[i], bv = ebp[i];
            da += zv.x*av.x + zv.y*av.y + zv.z*av.z + zv.w*av.w;
            db += zv.x*bv.x + zv.y*bv.y + zv.z*bv.z + zv.w*bv.w;
        }
        da += __shfl_xor(da, 1, 4); da += __shfl_xor(da, 2, 4);
        db += __shfl_xor(db, 1, 4); db += __shfl_xor(db, 2, 4);
        if (q == 0) {
            float z2 = znt2[t];
            float d1 = (z2 + en2s[c1]) - 2.0f * da;
            float d2 = (z2 + en2s[c2]) - 2.0f * db;
            int k = (d2 < d1 || (d2 == d1 && c2 < c1)) ? (int)c2 : (int)c1;
            idxb[t] = k;
            idxf[t] = (float)k;
        }
    }
}

// ---------------- K4: gather epilogue (quant = emb[idx], NCHW, float4) ------
__global__ void k_gather(const float* __restrict__ emb,
                         const int* __restrict__ idxb, float* __restrict__ out) {
    int o4  = blockIdx.x * 256 + threadIdx.x;  // float4 index
    int hw4 = o4 & 255;
    int nc  = o4 >> 8;
    int c   = nc & 255;
    int n   = nc >> 8;
    int tb  = (n << 10) | (hw4 << 2);
    int4 kk = *reinterpret_cast<const int4*>(idxb + tb);
    float4 r;
    r.x = emb[(size_t)kk.x * CDIM + c];
    r.y = emb[(size_t)kk.y * CDIM + c];
    r.z = emb[(size_t)kk.z * CDIM + c];
    r.w = emb[(size_t)kk.w * CDIM + c];
    reinterpret_cast<float4*>(out)[o4] = r;
}

extern "C" void kernel_launch(void* const* d_in, const int* in_sizes, int n_in,
                              void* d_out, int out_size, void* d_ws, size_t ws_size,
                              hipStream_t stream) {
    const float* z   = (const float*)d_in[0];
    const float* emb = (const float*)d_in[1];
    float* out  = (float*)d_out;
    float* znt  = out;                          // quant region doubles as zn scratch
    float* idxf = out + (size_t)NTOK * CDIM;    // index output (float) tail

    float*  en   = (float*)d_ws;                        // 1 MB
    float*  en2  = en + (size_t)KCODE * CDIM;           // 4 KB
    float*  znt2 = en2 + KCODE;                         // 128 KB
    __bf16* eh   = (__bf16*)(znt2 + NTOK);              // 512 KB
    __bf16* el   = eh + (size_t)KCODE * CDIM;           // 512 KB
    __bf16* zh   = el + (size_t)KCODE * CDIM;           // 16 MB
    __bf16* zl   = zh + (size_t)NTOK * CDIM;            // 16 MB
    int*    idxb = (int*)(zl + (size_t)NTOK * CDIM);    // 128 KB

    k_norm_emb<<<KCODE, 64, 0, stream>>>(emb, en, en2, eh, el);
    k_norm_z<<<NTOK / 32, 256, 0, stream>>>(z, znt, znt2, zh, zl);
    k_mfma<<<NTOK / 64, 256, 0, stream>>>(zh, zl, eh, el, en2, znt, znt2, en, idxb, idxf);
    k_gather<<<(NTOK * CDIM) / 4 / 256, 256, 0, stream>>>(emb, idxb, out);
}

// Round 7
// 133.538 us; speedup vs baseline: 1.0196x; 1.0196x over previous
//
#include <hip/hip_runtime.h>

#define NTOK 32768
#define CDIM 256
#define KCODE 1024
#define C4 64   // CDIM/4

typedef __bf16 bf16x8 __attribute__((ext_vector_type(8)));
typedef float  f32x4  __attribute__((ext_vector_type(4)));
typedef const __attribute__((address_space(1))) void* as1cvp;
typedef __attribute__((address_space(3))) void* as3vp;

__device__ __forceinline__ unsigned long long umin64(unsigned long long a, unsigned long long b) { return a < b ? a : b; }
__device__ __forceinline__ unsigned long long umax64(unsigned long long a, unsigned long long b) { return a > b ? a : b; }

// ---------------- K1: normalize codebook -> en fp32, en2, eh/el bf16 --------
__global__ void k_norm_emb(const float* __restrict__ emb,
                           float* __restrict__ en, float* __restrict__ en2,
                           __bf16* __restrict__ eh, __bf16* __restrict__ el) {
    int k = blockIdx.x;
    int l = threadIdx.x;               // 64 lanes, 4 floats each
    float4 v = reinterpret_cast<const float4*>(emb)[k * C4 + l];
    float ss = v.x*v.x + v.y*v.y + v.z*v.z + v.w*v.w;
    #pragma unroll
    for (int o = 32; o >= 1; o >>= 1) ss += __shfl_xor(ss, o, 64);
    float den = fmaxf(sqrtf(ss), 1e-12f);
    float4 e;
    e.x = v.x / den; e.y = v.y / den; e.z = v.z / den; e.w = v.w / den;
    reinterpret_cast<float4*>(en)[k * C4 + l] = e;
    float s2 = e.x*e.x + e.y*e.y + e.z*e.z + e.w*e.w;
    #pragma unroll
    for (int o = 32; o >= 1; o >>= 1) s2 += __shfl_xor(s2, o, 64);
    if (l == 0) en2[k] = s2;

    __bf16* ehp = eh + (size_t)k * CDIM + 4 * l;
    __bf16* elp = el + (size_t)k * CDIM + 4 * l;
    float ev[4] = {e.x, e.y, e.z, e.w};
    #pragma unroll
    for (int q = 0; q < 4; ++q) {
        __bf16 h = (__bf16)ev[q];
        ehp[q] = h;
        elp[q] = (__bf16)(ev[q] - (float)h);
    }
}

// ---------------- K2: transpose+normalize z -> znt fp32, znt2, zh/zl bf16 ---
__global__ void k_norm_z(const float* __restrict__ z,
                         float* __restrict__ znt, float* __restrict__ znt2,
                         __bf16* __restrict__ zh, __bf16* __restrict__ zl) {
    __shared__ float zsb[CDIM * 32];   // 32 KB, [c][ (tok+c)&31 ]
    __shared__ float ssp[256];
    __shared__ float dens[32];
    int tid = threadIdx.x;
    int t0  = blockIdx.x * 32;
    int n   = t0 >> 10;
    int thw0 = t0 & 1023;

    int l = tid & 31, grp = tid >> 5;          // 8 c-stripes
    const float* zb = z + (((size_t)(n * CDIM)) << 10) + thw0 + l;
    float ss = 0.f;
    int c0 = grp * 32;
    for (int cc = 0; cc < 32; ++cc) {
        int c = c0 + cc;
        float v = zb[((size_t)c) << 10];
        zsb[c * 32 + ((l + c) & 31)] = v;
        ss += v * v;
    }
    ssp[tid] = ss;
    __syncthreads();
    if (tid < 32) {
        float tot = 0.f;
        #pragma unroll
        for (int g = 0; g < 8; ++g) tot += ssp[g * 32 + tid];
        dens[tid] = fmaxf(sqrtf(tot), 1e-12f);
    }
    __syncthreads();

    int l2 = tid & 63, tg = tid >> 6;          // 4 token-groups of 8
    for (int it = 0; it < 8; ++it) {
        int tok = tg * 8 + it;
        float den = dens[tok];
        float s2 = 0.f;
        #pragma unroll
        for (int cq = 0; cq < 4; ++cq) {
            int c = cq * 64 + l2;
            float v = zsb[c * 32 + ((tok + c) & 31)] / den;
            size_t off = ((size_t)(t0 + tok)) * CDIM + c;
            znt[off] = v;
            __bf16 h = (__bf16)v;
            zh[off] = h;
            zl[off] = (__bf16)(v - (float)h);
            s2 += v * v;
        }
        #pragma unroll
        for (int o = 32; o >= 1; o >>= 1) s2 += __shfl_xor(s2, o, 64);
        if (l2 == 0) znt2[t0 + tok] = s2;
    }
}

// ---------------- K3: split-bf16 MFMA GEMM + top-2 + fused fp32 fixup -------
// 512 blocks x 256 threads (4 waves: 2M x 2N). BM=64 tokens, 32 chunks of 32
// codes, ~69KB LDS -> 2 blocks/CU. Counted-vmcnt pipeline (T3/T4): raw
// s_barrier + s_waitcnt vmcnt(8) so next chunk's global_load_lds stay in
// flight across the barrier. T5 setprio around the MFMA cluster.
__global__ __launch_bounds__(256, 2) void k_mfma(
        const __bf16* __restrict__ zh, const __bf16* __restrict__ zl,
        const __bf16* __restrict__ eh, const __bf16* __restrict__ el,
        const float* __restrict__ en2g,
        const float* __restrict__ znt, const float* __restrict__ znt2,
        const float* __restrict__ en,
        int* __restrict__ idxb, float* __restrict__ idxf) {
    __shared__ __bf16 ebuf[2][2][32 * 256];    // [buf][h/l], 16KB each = 64KB
    __shared__ float en2s[KCODE];              // 4KB
    __shared__ unsigned long long cand[64][2]; // 1KB

    int tid = threadIdx.x;
    int l = tid & 63, wid = tid >> 6;
    int mw = wid >> 1, nw = wid & 1;           // 2M x 2N
    int t0 = blockIdx.x * 64;
    int row = l & 15, kg = l >> 4;             // frag row / k-group

    for (int i = tid; i < KCODE; i += 256) en2s[i] = en2g[i];

    // hoist A: 2 mtiles x 8 ksteps x {hi,lo} = 128 VGPR, z read once
    bf16x8 ah[2][8], al_[2][8];
    #pragma unroll
    for (int mt = 0; mt < 2; ++mt) {
        size_t tok = (size_t)(t0 + mw * 32 + mt * 16 + row);
        const __bf16* ph = zh + tok * CDIM + kg * 8;
        const __bf16* pl = zl + tok * CDIM + kg * 8;
        #pragma unroll
        for (int ks = 0; ks < 8; ++ks) {
            ah[mt][ks]  = *reinterpret_cast<const bf16x8*>(ph + ks * 32);
            al_[mt][ks] = *reinterpret_cast<const bf16x8*>(pl + ks * 32);
        }
    }

    // top-2 keys per lane: 2 mtiles x 4 rows
    unsigned long long b1[8], b2[8];
    #pragma unroll
    for (int i = 0; i < 8; ++i) { b1[i] = ~0ull; b2[i] = ~0ull; }

    // stage one 32-code chunk (hi+lo): 8 global_load_lds per thread.
    // stored slot = c16 ^ (code & 15); dest lane-linear (wave-uniform base).
    auto stage = [&](int buf, int ch) {
        #pragma unroll
        for (int a = 0; a < 2; ++a) {
            const __bf16* src = a ? el : eh;
            #pragma unroll
            for (int i2 = 0; i2 < 4; ++i2) {
                int s = i2 * 256 + tid;
                int code = s >> 5, c16 = s & 31;
                int gslot = c16 ^ (code & 15);
                const __bf16* gp = src + ((size_t)(ch * 32 + code)) * CDIM + gslot * 8;
                __bf16* ld = &ebuf[buf][a][0] + ((size_t)(i2 * 256 + wid * 64)) * 8;
                __builtin_amdgcn_global_load_lds((as1cvp)gp, (as3vp)ld, 16, 0, 0);
            }
        }
    };

    stage(0, 0);
    #pragma unroll 2
    for (int ch = 0; ch < 32; ++ch) {
        int cur = ch & 1;
        // issue next chunk's loads, then wait only for buf[cur]'s 8 (oldest)
        if (ch < 31) {
            stage(cur ^ 1, ch + 1);
            asm volatile("s_waitcnt vmcnt(8)" ::: "memory");
        } else {
            asm volatile("s_waitcnt vmcnt(0)" ::: "memory");
        }
        __builtin_amdgcn_s_barrier();      // buf[cur] ready for all waves

        const __bf16* bh_base = &ebuf[cur][0][0];
        const __bf16* bl_base = &ebuf[cur][1][0];

        f32x4 a0[2], a1[2], a2[2];
        #pragma unroll
        for (int mt = 0; mt < 2; ++mt)
            #pragma unroll
            for (int r = 0; r < 4; ++r) { a0[mt][r] = 0.f; a1[mt][r] = 0.f; a2[mt][r] = 0.f; }

        int code_l = nw * 16 + row;
        __builtin_amdgcn_s_setprio(1);
        #pragma unroll
        for (int ks = 0; ks < 8; ++ks) {
            int slot = (ks * 4 + kg) ^ row;
            bf16x8 bh = *reinterpret_cast<const bf16x8*>(bh_base + code_l * 256 + slot * 8);
            bf16x8 bl = *reinterpret_cast<const bf16x8*>(bl_base + code_l * 256 + slot * 8);
            #pragma unroll
            for (int mt = 0; mt < 2; ++mt) {
                a0[mt] = __builtin_amdgcn_mfma_f32_16x16x32_bf16(ah[mt][ks],  bh, a0[mt], 0, 0, 0);
                a1[mt] = __builtin_amdgcn_mfma_f32_16x16x32_bf16(ah[mt][ks],  bl, a1[mt], 0, 0, 0);
                a2[mt] = __builtin_amdgcn_mfma_f32_16x16x32_bf16(al_[mt][ks], bh, a2[mt], 0, 0, 0);
            }
        }
        __builtin_amdgcn_s_setprio(0);

        // selection epilogue: d' = e2 - 2*dot; code col = lane&15
        int code = ch * 32 + code_l;
        float e2v = en2s[code];
        #pragma unroll
        for (int mt = 0; mt < 2; ++mt)
            #pragma unroll
            for (int r = 0; r < 4; ++r) {
                float d = fmaf(-2.0f, (a0[mt][r] + a1[mt][r]) + a2[mt][r], e2v);
                unsigned ub = __float_as_uint(d);
                ub = (ub & 0x80000000u) ? ~ub : (ub | 0x80000000u);
                unsigned long long key = ((unsigned long long)ub << 32) | (unsigned)code;
                int idx = mt * 4 + r;
                if (key < b1[idx]) { b2[idx] = b1[idx]; b1[idx] = key; }
                else if (key < b2[idx]) { b2[idx] = key; }
            }
        __builtin_amdgcn_s_barrier();      // all waves done reading buf[cur]
    }

    // butterfly top-2 merge across the 16 code-col lanes
    #pragma unroll
    for (int i = 0; i < 8; ++i) {
        #pragma unroll
        for (int off = 1; off < 16; off <<= 1) {
            unsigned long long o1 = __shfl_xor(b1[i], off, 16);
            unsigned long long o2 = __shfl_xor(b2[i], off, 16);
            unsigned long long m1 = umin64(b1[i], o1);
            unsigned long long m2 = umin64(umax64(b1[i], o1), umin64(b2[i], o2));
            b1[i] = m1; b2[i] = m2;
        }
    }
    // cross-wave (2N) merge via LDS: both nw write, then nw==0 merges
    if ((l & 15) == 0) {
        #pragma unroll
        for (int mt = 0; mt < 2; ++mt)
            #pragma unroll
            for (int r = 0; r < 4; ++r) {
                int tl = mw * 32 + mt * 16 + kg * 4 + r;   // C/D row mapping
                if (nw == 0) { cand[tl][0] = b1[mt * 4 + r]; cand[tl][1] = b2[mt * 4 + r]; }
            }
    }
    __syncthreads();
    if ((l & 15) == 0 && nw == 1) {
        #pragma unroll
        for (int mt = 0; mt < 2; ++mt)
            #pragma unroll
            for (int r = 0; r < 4; ++r) {
                int tl = mw * 32 + mt * 16 + kg * 4 + r;
                unsigned long long a1k = cand[tl][0], a2k = cand[tl][1];
                unsigned long long c1k = b1[mt * 4 + r], c2k = b2[mt * 4 + r];
                cand[tl][0] = umin64(a1k, c1k);
                cand[tl][1] = umin64(umax64(a1k, c1k), umin64(a2k, c2k));
            }
    }
    __syncthreads();

    // fused fp32 fixup: 4 threads per token, 64 dims each
    {
        int tl = tid >> 2, q = tid & 3;
        int t = t0 + tl;
        unsigned c1 = (unsigned)cand[tl][0];
        unsigned c2 = (unsigned)cand[tl][1];
        const float4* zp  = reinterpret_cast<const float4*>(znt) + (size_t)t  * C4 + q * 16;
        const float4* eap = reinterpret_cast<const float4*>(en)  + (size_t)c1 * C4 + q * 16;
        const float4* ebp = reinterpret_cast<const float4*>(en)  + (size_t)c2 * C4 + q * 16;
        float da = 0.f, db = 0.f;
        #pragma unroll
        for (int i = 0; i < 16; ++i) {
            float4 zv = zp[i], av = eap[i], bv = ebp[i];
            da += zv.x*av.x + zv.y*av.y + zv.z*av.z + zv.w*av.w;
            db += zv.x*bv.x + zv.y*bv.y + zv.z*bv.z + zv.w*bv.w;
        }
        da += __shfl_xor(da, 1, 4); da += __shfl_xor(da, 2, 4);
        db += __shfl_xor(db, 1, 4); db += __shfl_xor(db, 2, 4);
        if (q == 0) {
            float z2 = znt2[t];
            float d1 = (z2 + en2s[c1]) - 2.0f * da;
            float d2 = (z2 + en2s[c2]) - 2.0f * db;
            int k = (d2 < d1 || (d2 == d1 && c2 < c1)) ? (int)c2 : (int)c1;
            idxb[t] = k;
            idxf[t] = (float)k;
        }
    }
}

// ---------------- K4: gather epilogue (quant = emb[idx], NCHW, float4) ------
__global__ void k_gather(const float* __restrict__ emb,
                         const int* __restrict__ idxb, float* __restrict__ out) {
    int o4  = blockIdx.x * 256 + threadIdx.x;  // float4 index
    int hw4 = o4 & 255;
    int nc  = o4 >> 8;
    int c   = nc & 255;
    int n   = nc >> 8;
    int tb  = (n << 10) | (hw4 << 2);
    int4 kk = *reinterpret_cast<const int4*>(idxb + tb);
    float4 r;
    r.x = emb[(size_t)kk.x * CDIM + c];
    r.y = emb[(size_t)kk.y * CDIM + c];
    r.z = emb[(size_t)kk.z * CDIM + c];
    r.w = emb[(size_t)kk.w * CDIM + c];
    reinterpret_cast<float4*>(out)[o4] = r;
}

extern "C" void kernel_launch(void* const* d_in, const int* in_sizes, int n_in,
                              void* d_out, int out_size, void* d_ws, size_t ws_size,
                              hipStream_t stream) {
    const float* z   = (const float*)d_in[0];
    const float* emb = (const float*)d_in[1];
    float* out  = (float*)d_out;
    float* znt  = out;                          // quant region doubles as zn scratch
    float* idxf = out + (size_t)NTOK * CDIM;    // index output (float) tail

    float*  en   = (float*)d_ws;                        // 1 MB
    float*  en2  = en + (size_t)KCODE * CDIM;           // 4 KB
    float*  znt2 = en2 + KCODE;                         // 128 KB
    __bf16* eh   = (__bf16*)(znt2 + NTOK);              // 512 KB
    __bf16* el   = eh + (size_t)KCODE * CDIM;           // 512 KB
    __bf16* zh   = el + (size_t)KCODE * CDIM;           // 16 MB
    __bf16* zl   = zh + (size_t)NTOK * CDIM;            // 16 MB
    int*    idxb = (int*)(zl + (size_t)NTOK * CDIM);    // 128 KB

    k_norm_emb<<<KCODE, 64, 0, stream>>>(emb, en, en2, eh, el);
    k_norm_z<<<NTOK / 32, 256, 0, stream>>>(z, znt, znt2, zh, zl);
    k_mfma<<<NTOK / 64, 256, 0, stream>>>(zh, zl, eh, el, en2, znt, znt2, en, idxb, idxf);
    k_gather<<<(NTOK * CDIM) / 4 / 256, 256, 0, stream>>>(emb, idxb, out);
}

// Round 8
// 100.883 us; speedup vs baseline: 1.3496x; 1.3237x over previous
//
#include <hip/hip_runtime.h>

#define NTOK 32768
#define CDIM 256
#define KCODE 1024
#define C4 64   // CDIM/4

typedef __bf16 bf16x8 __attribute__((ext_vector_type(8)));
typedef float  f32x4  __attribute__((ext_vector_type(4)));
typedef const __attribute__((address_space(1))) void* as1cvp;
typedef __attribute__((address_space(3))) void* as3vp;

__device__ __forceinline__ unsigned long long umin64(unsigned long long a, unsigned long long b) { return a < b ? a : b; }
__device__ __forceinline__ unsigned long long umax64(unsigned long long a, unsigned long long b) { return a > b ? a : b; }

// ---------------- K1: normalize codebook -> en fp32, en2, eh/el bf16 --------
__global__ void k_norm_emb(const float* __restrict__ emb,
                           float* __restrict__ en, float* __restrict__ en2,
                           __bf16* __restrict__ eh, __bf16* __restrict__ el) {
    int k = blockIdx.x;
    int l = threadIdx.x;               // 64 lanes, 4 floats each
    float4 v = reinterpret_cast<const float4*>(emb)[k * C4 + l];
    float ss = v.x*v.x + v.y*v.y + v.z*v.z + v.w*v.w;
    #pragma unroll
    for (int o = 32; o >= 1; o >>= 1) ss += __shfl_xor(ss, o, 64);
    float den = fmaxf(sqrtf(ss), 1e-12f);
    float4 e;
    e.x = v.x / den; e.y = v.y / den; e.z = v.z / den; e.w = v.w / den;
    reinterpret_cast<float4*>(en)[k * C4 + l] = e;
    float s2 = e.x*e.x + e.y*e.y + e.z*e.z + e.w*e.w;
    #pragma unroll
    for (int o = 32; o >= 1; o >>= 1) s2 += __shfl_xor(s2, o, 64);
    if (l == 0) en2[k] = s2;

    __bf16* ehp = eh + (size_t)k * CDIM + 4 * l;
    __bf16* elp = el + (size_t)k * CDIM + 4 * l;
    float ev[4] = {e.x, e.y, e.z, e.w};
    #pragma unroll
    for (int q = 0; q < 4; ++q) {
        __bf16 h = (__bf16)ev[q];
        ehp[q] = h;
        elp[q] = (__bf16)(ev[q] - (float)h);
    }
}

// ---------------- K2: transpose+normalize z -> znt fp32 + znt2 --------------
__global__ void k_norm_z(const float* __restrict__ z,
                         float* __restrict__ znt, float* __restrict__ znt2) {
    __shared__ float zsb[CDIM * 32];   // 32 KB, [c][ (tok+c)&31 ]
    __shared__ float ssp[256];
    __shared__ float dens[32];
    int tid = threadIdx.x;
    int t0  = blockIdx.x * 32;
    int n   = t0 >> 10;
    int thw0 = t0 & 1023;

    int l = tid & 31, grp = tid >> 5;          // 8 c-stripes
    const float* zb = z + (((size_t)(n * CDIM)) << 10) + thw0 + l;
    float ss = 0.f;
    int c0 = grp * 32;
    for (int cc = 0; cc < 32; ++cc) {
        int c = c0 + cc;
        float v = zb[((size_t)c) << 10];
        zsb[c * 32 + ((l + c) & 31)] = v;
        ss += v * v;
    }
    ssp[tid] = ss;
    __syncthreads();
    if (tid < 32) {
        float tot = 0.f;
        #pragma unroll
        for (int g = 0; g < 8; ++g) tot += ssp[g * 32 + tid];
        dens[tid] = fmaxf(sqrtf(tot), 1e-12f);
    }
    __syncthreads();

    int l2 = tid & 63, tg = tid >> 6;          // 4 token-groups of 8
    for (int it = 0; it < 8; ++it) {
        int tok = tg * 8 + it;
        float den = dens[tok];
        float s2 = 0.f;
        #pragma unroll
        for (int cq = 0; cq < 4; ++cq) {
            int c = cq * 64 + l2;
            float v = zsb[c * 32 + ((tok + c) & 31)] / den;
            znt[((size_t)(t0 + tok)) * CDIM + c] = v;
            s2 += v * v;
        }
        #pragma unroll
        for (int o = 32; o >= 1; o >>= 1) s2 += __shfl_xor(s2, o, 64);
        if (l2 == 0) znt2[t0 + tok] = s2;
    }
}

// ---------------- K3: MFMA GEMM + top-2 + fused fixup + fused gather --------
// 512 blocks x 256 threads (4 waves: 2M x 2N) — r5's proven main loop.
// A read from fp32 znt once, split hi/lo in regs. B (eh/el) double-buffered
// in LDS via global_load_lds with pre-swizzled source. Epilogue fused:
// top-2 merge -> fp32 fixup -> emb-row LDS stage -> coalesced NCHW writes.
__global__ __launch_bounds__(256, 2) void k_mfma(
        const float* __restrict__ znt,
        const __bf16* __restrict__ eh, const __bf16* __restrict__ el,
        const float* __restrict__ en2g,
        const float* __restrict__ znt2, const float* __restrict__ en,
        const float* __restrict__ emb, float* __restrict__ out) {
    // union: [0,65536) ebuf | [65536,69632) en2s ; gather reuses [0,65792) as qt[64][257]
    __shared__ __align__(16) char smem_u[69632];
    __shared__ unsigned long long t2l[64][2][2];
    __shared__ int idxs[64];
    __bf16* ebuf = reinterpret_cast<__bf16*>(smem_u);            // [2][2][8192]
    float*  en2s = reinterpret_cast<float*>(smem_u + 65536);     // [1024]
    float*  qt   = reinterpret_cast<float*>(smem_u);             // [64][257]

    int tid = threadIdx.x;
    int l = tid & 63, wid = tid >> 6;
    int mw = wid >> 1, nw = wid & 1;           // 2M x 2N
    int t0 = blockIdx.x * 64;
    int row = l & 15, kg = l >> 4;             // frag row / k-group

    for (int i = tid; i < KCODE; i += 256) en2s[i] = en2g[i];

    // hoist A from fp32 znt, split hi/lo: 2 mt x 8 ks x {h,l} = 128 VGPR
    bf16x8 ah[2][8], al_[2][8];
    #pragma unroll
    for (int mt = 0; mt < 2; ++mt) {
        size_t tok = (size_t)(t0 + mw * 32 + mt * 16 + row);
        const float* pz = znt + tok * CDIM + kg * 8;
        #pragma unroll
        for (int ks = 0; ks < 8; ++ks) {
            float f[8];
            *reinterpret_cast<float4*>(&f[0]) = *reinterpret_cast<const float4*>(pz + ks * 32);
            *reinterpret_cast<float4*>(&f[4]) = *reinterpret_cast<const float4*>(pz + ks * 32 + 4);
            bf16x8 h, lo;
            #pragma unroll
            for (int q = 0; q < 8; ++q) {
                __bf16 hv = (__bf16)f[q];
                h[q] = hv;
                lo[q] = (__bf16)(f[q] - (float)hv);
            }
            ah[mt][ks] = h; al_[mt][ks] = lo;
        }
    }

    // top-2 keys per lane: 2 mtiles x 4 rows
    unsigned long long b1[8], b2[8];
    #pragma unroll
    for (int i = 0; i < 8; ++i) { b1[i] = ~0ull; b2[i] = ~0ull; }

    // stage one 32-code chunk (hi+lo) with XOR swizzle (slot = c16 ^ (code&15))
    auto stage = [&](int buf, int ch) {
        #pragma unroll
        for (int a = 0; a < 2; ++a) {
            const __bf16* src = a ? el : eh;
            #pragma unroll
            for (int i2 = 0; i2 < 4; ++i2) {
                int s = i2 * 256 + tid;
                int code = s >> 5, c16 = s & 31;
                int gslot = c16 ^ (code & 15);
                const __bf16* gp = src + ((size_t)(ch * 32 + code)) * CDIM + gslot * 8;
                __bf16* ld = ebuf + (size_t)(buf * 2 + a) * 8192 + (size_t)(i2 * 256 + wid * 64) * 8;
                __builtin_amdgcn_global_load_lds((as1cvp)gp, (as3vp)ld, 16, 0, 0);
            }
        }
    };

    stage(0, 0);
    __syncthreads();
    #pragma unroll 2
    for (int ch = 0; ch < 32; ++ch) {
        int cur = ch & 1;
        if (ch < 31) stage(cur ^ 1, ch + 1);

        const __bf16* bh_base = ebuf + (size_t)(cur * 2 + 0) * 8192;
        const __bf16* bl_base = ebuf + (size_t)(cur * 2 + 1) * 8192;

        f32x4 a0[2], a1[2], a2[2];
        #pragma unroll
        for (int mt = 0; mt < 2; ++mt)
            #pragma unroll
            for (int r = 0; r < 4; ++r) { a0[mt][r] = 0.f; a1[mt][r] = 0.f; a2[mt][r] = 0.f; }

        int code_l = nw * 16 + row;
        #pragma unroll
        for (int ks = 0; ks < 8; ++ks) {
            int slot = (ks * 4 + kg) ^ row;
            bf16x8 bh = *reinterpret_cast<const bf16x8*>(bh_base + code_l * 256 + slot * 8);
            bf16x8 bl = *reinterpret_cast<const bf16x8*>(bl_base + code_l * 256 + slot * 8);
            #pragma unroll
            for (int mt = 0; mt < 2; ++mt) {
                a0[mt] = __builtin_amdgcn_mfma_f32_16x16x32_bf16(ah[mt][ks],  bh, a0[mt], 0, 0, 0);
                a1[mt] = __builtin_amdgcn_mfma_f32_16x16x32_bf16(ah[mt][ks],  bl, a1[mt], 0, 0, 0);
                a2[mt] = __builtin_amdgcn_mfma_f32_16x16x32_bf16(al_[mt][ks], bh, a2[mt], 0, 0, 0);
            }
        }

        // selection epilogue: d' = e2 - 2*dot; code col = lane&15
        int code = ch * 32 + code_l;
        float e2v = en2s[code];
        #pragma unroll
        for (int mt = 0; mt < 2; ++mt)
            #pragma unroll
            for (int r = 0; r < 4; ++r) {
                float d = fmaf(-2.0f, (a0[mt][r] + a1[mt][r]) + a2[mt][r], e2v);
                unsigned ub = __float_as_uint(d);
                ub = (ub & 0x80000000u) ? ~ub : (ub | 0x80000000u);
                unsigned long long key = ((unsigned long long)ub << 32) | (unsigned)code;
                int idx = mt * 4 + r;
                if (key < b1[idx]) { b2[idx] = b1[idx]; b1[idx] = key; }
                else if (key < b2[idx]) { b2[idx] = key; }
            }
        __syncthreads();
    }

    // butterfly top-2 merge across the 16 code-col lanes
    #pragma unroll
    for (int i = 0; i < 8; ++i) {
        #pragma unroll
        for (int off = 1; off < 16; off <<= 1) {
            unsigned long long o1 = __shfl_xor(b1[i], off, 16);
            unsigned long long o2 = __shfl_xor(b2[i], off, 16);
            unsigned long long m1 = umin64(b1[i], o1);
            unsigned long long m2 = umin64(umax64(b1[i], o1), umin64(b2[i], o2));
            b1[i] = m1; b2[i] = m2;
        }
    }
    if ((l & 15) == 0) {
        #pragma unroll
        for (int mt = 0; mt < 2; ++mt)
            #pragma unroll
            for (int r = 0; r < 4; ++r) {
                int tl = mw * 32 + mt * 16 + kg * 4 + r;   // C/D row mapping
                t2l[tl][nw][0] = b1[mt * 4 + r];
                t2l[tl][nw][1] = b2[mt * 4 + r];
            }
    }
    __syncthreads();

    // fused fp32 fixup: 4 threads per token, 64 dims each
    {
        int tl = tid >> 2, q = tid & 3;
        int t = t0 + tl;
        unsigned long long x1 = t2l[tl][0][0], x2 = t2l[tl][0][1];
        unsigned long long y1 = t2l[tl][1][0], y2 = t2l[tl][1][1];
        unsigned c1 = (unsigned)umin64(x1, y1);
        unsigned c2 = (unsigned)umin64(umax64(x1, y1), umin64(x2, y2));
        const float4* zp  = reinterpret_cast<const float4*>(znt) + (size_t)t  * C4 + q * 16;
        const float4* eap = reinterpret_cast<const float4*>(en)  + (size_t)c1 * C4 + q * 16;
        const float4* ebp = reinterpret_cast<const float4*>(en)  + (size_t)c2 * C4 + q * 16;
        float da = 0.f, db = 0.f;
        #pragma unroll
        for (int i = 0; i < 16; ++i) {
            float4 zv = zp[i], av = eap[i], bv = ebp[i];
            da += zv.x*av.x + zv.y*av.y + zv.z*av.z + zv.w*av.w;
            db += zv.x*bv.x + zv.y*bv.y + zv.z*bv.z + zv.w*bv.w;
        }
        da += __shfl_xor(da, 1, 4); da += __shfl_xor(da, 2, 4);
        db += __shfl_xor(db, 1, 4); db += __shfl_xor(db, 2, 4);
        if (q == 0) {
            float z2 = znt2[t];
            float d1 = (z2 + en2s[c1]) - 2.0f * da;
            float d2 = (z2 + en2s[c2]) - 2.0f * db;
            int k = (d2 < d1 || (d2 == d1 && c2 < c1)) ? (int)c2 : (int)c1;
            idxs[tl] = k;
            out[(size_t)NTOK * CDIM + t] = (float)k;   // index output tail
        }
    }
    __syncthreads();   // fixup reads of en2s done; idxs visible; qt may overwrite

    // fused gather stage: emb row of each token -> qt[64][257] (padded)
    {
        int tl = tid >> 2, q = tid & 3;
        int kidx = idxs[tl];
        const float4* ep = reinterpret_cast<const float4*>(emb + (size_t)kidx * CDIM + q * 64);
        #pragma unroll
        for (int i = 0; i < 16; ++i) {
            float4 v = ep[i];
            int cb = q * 64 + i * 4;
            qt[tl * 257 + cb + 0] = v.x;
            qt[tl * 257 + cb + 1] = v.y;
            qt[tl * 257 + cb + 2] = v.z;
            qt[tl * 257 + cb + 3] = v.w;
        }
    }
    __syncthreads();

    // transpose write: lanes = hw (coalesced 256B stores), NCHW
    {
        int hwo = tid & 63, cg = tid >> 6;     // 4 c-groups of 64
        int n = t0 >> 10, hw = (t0 & 1023) + hwo;
        float* ob = out + (size_t)n * (CDIM * 1024) + hw;
        #pragma unroll 8
        for (int cc = 0; cc < 64; ++cc) {
            int c = cg * 64 + cc;
            ob[(size_t)c * 1024] = qt[hwo * 257 + c];
        }
    }
}

extern "C" void kernel_launch(void* const* d_in, const int* in_sizes, int n_in,
                              void* d_out, int out_size, void* d_ws, size_t ws_size,
                              hipStream_t stream) {
    const float* z   = (const float*)d_in[0];
    const float* emb = (const float*)d_in[1];
    float* out  = (float*)d_out;

    float*  en   = (float*)d_ws;                        // 1 MB
    float*  en2  = en + (size_t)KCODE * CDIM;           // 4 KB
    float*  znt2 = en2 + KCODE;                         // 128 KB
    __bf16* eh   = (__bf16*)(znt2 + NTOK);              // 512 KB
    __bf16* el   = eh + (size_t)KCODE * CDIM;           // 512 KB
    float*  znt  = (float*)(el + (size_t)KCODE * CDIM); // 32 MB

    k_norm_emb<<<KCODE, 64, 0, stream>>>(emb, en, en2, eh, el);
    k_norm_z<<<NTOK / 32, 256, 0, stream>>>(z, znt, znt2);
    k_mfma<<<NTOK / 64, 256, 0, stream>>>(znt, eh, el, en2, znt2, en, emb, out);
}